// Round 4
// baseline (3732.205 us; speedup 1.0000x reference)
//
#include <hip/hip_runtime.h>

#define NU 200000
#define NR 50000
#define DD 64
#define NE 2000000
#define NQ 500000
#define NBR 196   // ceil(NR/256)
#define NBU 782   // ceil(NU/256)

// ---- dst-windowed build parameters ----
#define NBS_U 98            // user dst windows (2048 rows each)
#define LW_U 11
#define CAP_U 24576         // mean 20480, +29 sigma
#define NBS_R 196           // restaurant dst windows (256 rows each)
#define LW_R 8
#define CAP_R 12288         // mean 10240, +20 sigma
#define PB_E 4096           // edges per binpass block
#define NPBB 489            // ceil(NE / PB_E)
#define SBINS 391           // ceil(NU / 512) src-sort chunks

// -------------------- binpass: bin (src,dst) pairs by dst window -----------
// side 0: ru edges (dst=user, 98 windows). side 1: ur edges (dst=rest, 196).
__global__ __launch_bounds__(256)
void binpass_kernel(const int* __restrict__ ru_src, const int* __restrict__ ru_dst,
                    const int* __restrict__ ur_src, const int* __restrict__ ur_dst,
                    int* __restrict__ bcur, int2* __restrict__ pairs) {
    __shared__ int2 stg[PB_E];
    __shared__ unsigned char gstg[PB_E];
    __shared__ int hist[256];
    __shared__ int sca[256], scb[256];
    __shared__ int gpos[256];
    int side = (blockIdx.x >= NPBB) ? 1 : 0;
    int blk = side ? (blockIdx.x - NPBB) : blockIdx.x;
    const int* src = side ? ur_src : ru_src;
    const int* dst = side ? ur_dst : ru_dst;
    int lw = side ? LW_R : LW_U;
    int nbs = side ? NBS_R : NBS_U;
    int cap = side ? CAP_R : CAP_U;
    int* bc = bcur + (side ? NBS_U : 0);
    int2* region = pairs + (side ? (size_t)NBS_U * CAP_U : 0);
    int tid = threadIdx.x;
    hist[tid] = 0;
    __syncthreads();
    int base = blk * PB_E;
    int myg[16]; int myrank[16]; int2 myp[16];
#pragma unroll
    for (int i = 0; i < 16; i++) {
        int e = base + i * 256 + tid;
        if (e < NE) {
            int d = dst[e];
            int g = d >> lw;
            myg[i] = g;
            myp[i] = make_int2(src[e], d);
            myrank[i] = atomicAdd(&hist[g], 1);
        } else myg[i] = -1;
    }
    __syncthreads();
    int h = hist[tid];
    sca[tid] = h;
    __syncthreads();
    int* cur = sca; int* alt = scb;
    for (int off = 1; off < 256; off <<= 1) {
        int x = cur[tid];
        if (tid >= off) x += cur[tid - off];
        alt[tid] = x;
        __syncthreads();
        int* tmp = cur; cur = alt; alt = tmp;
    }
    alt[tid] = cur[tid] - h;          // exclusive base per bucket
    if (tid < nbs && h > 0) gpos[tid] = atomicAdd(&bc[tid], h);
    __syncthreads();
    int* basep = alt;
#pragma unroll
    for (int i = 0; i < 16; i++) {
        if (myg[i] >= 0) {
            int p = basep[myg[i]] + myrank[i];
            stg[p] = myp[i];
            gstg[p] = (unsigned char)myg[i];
        }
    }
    __syncthreads();
    int tot = cur[255];
    for (int i = tid; i < tot; i += 256) {
        int g = gstg[i];
        int o = g * cap + gpos[g] + (i - basep[g]);
        region[o] = stg[i];
    }
}

// -------------------- ubase: scan 98 u-window totals -----------------------
__global__ void ubase_kernel(const int* __restrict__ bcur, int* __restrict__ bbase,
                             int* __restrict__ rs_u) {
    __shared__ int a[128], b[128];
    int tid = threadIdx.x;
    a[tid] = (tid < NBS_U) ? bcur[tid] : 0;
    __syncthreads();
    int* cur = a; int* alt = b;
    for (int off = 1; off < 128; off <<= 1) {
        int t = cur[tid];
        if (tid >= off) t += cur[tid - off];
        alt[tid] = t;
        __syncthreads();
        int* tmp = cur; cur = alt; alt = tmp;
    }
    if (tid < NBS_U) bbase[tid] = (tid == 0) ? 0 : cur[tid - 1];
    if (tid == 0) rs_u[NU] = NE;
}

// -------------------- fillpass (u-side): count/scan/scatter in LDS ---------
__global__ __launch_bounds__(256)
void fillpassu_kernel(const int2* __restrict__ pairs, const int* __restrict__ bcur,
                      const int* __restrict__ bbase,
                      int* __restrict__ rs_u, int* __restrict__ csr_u) {
    __shared__ int win[CAP_U];        // 96 KB CSR window image
    __shared__ int lcnt[2048];
    __shared__ int lofs[2048];
    __shared__ int tsc[256], tsc2[256];
    int bkt = blockIdx.x;
    const int2* reg = pairs + (size_t)bkt * CAP_U;
    int d0 = bkt << LW_U;
    int tot = bcur[bkt];
    int base = bbase[bkt];
    int tid = threadIdx.x;
    for (int i = tid; i < 2048; i += 256) lcnt[i] = 0;
    __syncthreads();
    for (int i = tid; i < tot; i += 256) {
        int2 p = reg[i];
        atomicAdd(&lcnt[p.y - d0], 1);
    }
    __syncthreads();
    int b0 = tid * 8;
    int run = 0;
    for (int i = 0; i < 8; i++) { int v = lcnt[b0 + i]; lofs[b0 + i] = run; run += v; }
    tsc[tid] = run;
    __syncthreads();
    int* cur = tsc; int* alt = tsc2;
    for (int off = 1; off < 256; off <<= 1) {
        int x = cur[tid];
        if (tid >= off) x += cur[tid - off];
        alt[tid] = x;
        __syncthreads();
        int* tmp = cur; cur = alt; alt = tmp;
    }
    int texcl = cur[tid] - run;
    for (int i = 0; i < 8; i++) lofs[b0 + i] += texcl;
    __syncthreads();
    int wn = min(2048, NU - d0);
    for (int i = tid; i < wn; i += 256) rs_u[d0 + i] = base + lofs[i];
    __syncthreads();
    for (int i = tid; i < tot; i += 256) {
        int2 p = reg[i];
        int slot = atomicAdd(&lofs[p.y - d0], 1);
        win[slot] = p.x;
    }
    __syncthreads();
    for (int i = tid; i < tot; i += 256) csr_u[base + i] = win[i];
}

// -------------------- srcsort: order r-window edges by src chunk -----------
// Counting sort by src>>9 (512-user chunks); also emits per-restaurant degree.
// Output packed: (src << 8) | (dst - d0).
__global__ __launch_bounds__(256)
void srcsort_kernel(const int2* __restrict__ pairs, const int* __restrict__ bcur,
                    int* __restrict__ pairs2, int* __restrict__ cnt_r) {
    __shared__ int hist[512];
    __shared__ int cntd[256];
    __shared__ int tsc[256], tsc2[256];
    int bkt = blockIdx.x;
    const int2* reg = pairs + (size_t)NBS_U * CAP_U + (size_t)bkt * CAP_R;
    int tot = bcur[NBS_U + bkt];
    int d0 = bkt << LW_R;
    int tid = threadIdx.x;
    hist[tid] = 0; hist[tid + 256] = 0; cntd[tid] = 0;
    __syncthreads();
    for (int i = tid; i < tot; i += 256) {
        int2 p = reg[i];
        atomicAdd(&hist[p.x >> 9], 1);
        atomicAdd(&cntd[p.y - d0], 1);
    }
    __syncthreads();
    int wn = min(256, NR - d0);
    if (tid < wn) cnt_r[d0 + tid] = cntd[tid];
    int b0 = tid * 2;
    int h0 = hist[b0], h1 = hist[b0 + 1];
    int run = h0 + h1;
    tsc[tid] = run;
    __syncthreads();
    int* cur = tsc; int* alt = tsc2;
    for (int off = 1; off < 256; off <<= 1) {
        int x = cur[tid];
        if (tid >= off) x += cur[tid - off];
        alt[tid] = x;
        __syncthreads();
        int* tmp = cur; cur = alt; alt = tmp;
    }
    int texcl = cur[tid] - run;
    __syncthreads();
    hist[b0] = texcl;
    hist[b0 + 1] = texcl + h0;
    __syncthreads();
    for (int i = tid; i < tot; i += 256) {
        int2 p = reg[i];
        int pos = atomicAdd(&hist[p.x >> 9], 1);
        pairs2[(size_t)bkt * CAP_R + pos] = (p.x << LW_R) | (p.y - d0);
    }
}

// -------------------- rscatter: src-ordered scatter into LDS window --------
// 196 blocks walk src 0..NU in lockstep (self-stabilizing via L2 feedback),
// so the active h_u footprint stays cache-resident; h_u fetched ~once.
__global__ __launch_bounds__(512, 1)
void rscatter_kernel(const float* __restrict__ hu, const int* __restrict__ pairs2,
                     const int* __restrict__ bcur, const int* __restrict__ cnt_r,
                     float* __restrict__ mean_r) {
    __shared__ float acc[256 * DD];   // 64 KB window accumulator
    int bkt = blockIdx.x;
    int tot = bcur[NBS_U + bkt];
    int d0 = bkt << LW_R;
    const int* reg = pairs2 + (size_t)bkt * CAP_R;
    int tid = threadIdx.x;
    for (int i = tid; i < 256 * DD; i += 512) acc[i] = 0.f;
    __syncthreads();
    int lane = tid & 63;
    int wv = tid >> 6;                // 8 waves
    for (int c = wv * 64; c < tot; c += 512) {
        int n = min(64, tot - c);
        int v = reg[c + (lane < n ? lane : n - 1)];
        for (int k = 0; k < n; k += 8) {
            int v0 = __shfl(v, k);
            int v1 = __shfl(v, k + 1);
            int v2 = __shfl(v, k + 2);
            int v3 = __shfl(v, k + 3);
            int v4 = __shfl(v, k + 4);
            int v5 = __shfl(v, k + 5);
            int v6 = __shfl(v, k + 6);
            int v7 = __shfl(v, k + 7);
            float x0 = hu[(size_t)(v0 >> LW_R) * DD + lane];
            float x1 = hu[(size_t)(v1 >> LW_R) * DD + lane];
            float x2 = hu[(size_t)(v2 >> LW_R) * DD + lane];
            float x3 = hu[(size_t)(v3 >> LW_R) * DD + lane];
            float x4 = hu[(size_t)(v4 >> LW_R) * DD + lane];
            float x5 = hu[(size_t)(v5 >> LW_R) * DD + lane];
            float x6 = hu[(size_t)(v6 >> LW_R) * DD + lane];
            float x7 = hu[(size_t)(v7 >> LW_R) * DD + lane];
            atomicAdd(&acc[(v0 & 255) * DD + lane], x0);
            if (k + 1 < n) atomicAdd(&acc[(v1 & 255) * DD + lane], x1);
            if (k + 2 < n) atomicAdd(&acc[(v2 & 255) * DD + lane], x2);
            if (k + 3 < n) atomicAdd(&acc[(v3 & 255) * DD + lane], x3);
            if (k + 4 < n) atomicAdd(&acc[(v4 & 255) * DD + lane], x4);
            if (k + 5 < n) atomicAdd(&acc[(v5 & 255) * DD + lane], x5);
            if (k + 6 < n) atomicAdd(&acc[(v6 & 255) * DD + lane], x6);
            if (k + 7 < n) atomicAdd(&acc[(v7 & 255) * DD + lane], x7);
        }
    }
    __syncthreads();
    int wn = min(256, NR - d0);
    for (int rr = wv; rr < wn; rr += 8) {
        float inv = 1.0f / fmaxf((float)cnt_r[d0 + rr], 1.0f);
        mean_r[(size_t)(d0 + rr) * DD + lane] = acc[rr * DD + lane] * inv;
    }
}

// -------------------- gatheru: wave per user row (h_r is cache-small) ------
__global__ __launch_bounds__(256)
void gatheru_kernel(const float* __restrict__ hr, const int* __restrict__ csr_u,
                    const int* __restrict__ rs_u, float* __restrict__ mean_u) {
    int lane = threadIdx.x & 63;
    int wave = blockIdx.x * 4 + (threadIdx.x >> 6);
    if (wave >= NU) return;
    int r = wave;
    int s = rs_u[r], e = rs_u[r + 1];
    float a0 = 0.f, a1 = 0.f, a2 = 0.f, a3 = 0.f;
    for (int j = s; j < e; j += 64) {
        int rem = e - j;
        int nch = rem < 64 ? rem : 64;
        int li = lane < nch ? lane : nch - 1;
        int idx = csr_u[j + li];
        for (int kk = 0; kk < nch; kk += 4) {
            int i0 = __shfl(idx, kk);
            int i1 = __shfl(idx, kk + 1);
            int i2 = __shfl(idx, kk + 2);
            int i3 = __shfl(idx, kk + 3);
            float v0 = hr[i0 * DD + lane];
            float v1 = hr[i1 * DD + lane];
            float v2 = hr[i2 * DD + lane];
            float v3 = hr[i3 * DD + lane];
            a0 += v0;
            a1 += (kk + 1 < nch) ? v1 : 0.f;
            a2 += (kk + 2 < nch) ? v2 : 0.f;
            a3 += (kk + 3 < nch) ? v3 : 0.f;
        }
    }
    float acc = (a0 + a1) + (a2 + a3);
    float inv = 1.0f / fmaxf((float)(e - s), 1.0f);
    mean_u[r * DD + lane] = acc * inv;
}

// ==== macro toolkit (sage/precompute: 4 rows/thread x 16 cols/wave) ====
#define DOT4(A, B) ((A).x*(B).x + (A).y*(B).y + (A).z*(B).z + (A).w*(B).w)

#define SDECL(j) float sA##j = bsh[cb + (j)], sB##j = sA##j, sC##j = sA##j, sD##j = sA##j;

#define SCOL(j) { \
    const float4* wlp_ = (const float4*)(Wls + ((cb + (j)) << 6) + kc); \
    const float4* wrp_ = (const float4*)(Wrs + ((cb + (j)) << 6) + kc); \
    float4 l0_ = wlp_[0], l1_ = wlp_[1], q0_ = wrp_[0], q1_ = wrp_[1]; \
    sA##j += DOT4(mA0,l0_)+DOT4(mA1,l1_)+DOT4(xA0,q0_)+DOT4(xA1,q1_); \
    sB##j += DOT4(mB0,l0_)+DOT4(mB1,l1_)+DOT4(xB0,q0_)+DOT4(xB1,q1_); \
    sC##j += DOT4(mC0,l0_)+DOT4(mC1,l1_)+DOT4(xC0,q0_)+DOT4(xC1,q1_); \
    sD##j += DOT4(mD0,l0_)+DOT4(mD1,l1_)+DOT4(xD0,q0_)+DOT4(xD1,q1_); }

#define SRELU(j) { sA##j = fmaxf(sA##j,0.f); sB##j = fmaxf(sB##j,0.f); \
                   sC##j = fmaxf(sC##j,0.f); sD##j = fmaxf(sD##j,0.f); }

#define STORE_ROW(SR, rr) if ((rr) < n) { \
    float* o_ = out + (size_t)(rr) * DD + cb; \
    *(float4*)(o_)      = {SR##0,  SR##1,  SR##2,  SR##3}; \
    *(float4*)(o_ + 4)  = {SR##4,  SR##5,  SR##6,  SR##7}; \
    *(float4*)(o_ + 8)  = {SR##8,  SR##9,  SR##10, SR##11}; \
    *(float4*)(o_ + 12) = {SR##12, SR##13, SR##14, SR##15}; }

__device__ __forceinline__
void sage_tile(const float* __restrict__ mean, const float* __restrict__ h,
               const float* Wls, const float* Wrs, const float* bsh,
               float* __restrict__ out, int n, int do_relu, int r0, int cb) {
    int rA = min(r0, n - 1), rB = min(r0 + 64, n - 1);
    int rC = min(r0 + 128, n - 1), rD = min(r0 + 192, n - 1);
    const float *mA = mean + (size_t)rA * DD, *xA = h + (size_t)rA * DD;
    const float *mB = mean + (size_t)rB * DD, *xB = h + (size_t)rB * DD;
    const float *mC = mean + (size_t)rC * DD, *xC = h + (size_t)rC * DD;
    const float *mD = mean + (size_t)rD * DD, *xD = h + (size_t)rD * DD;
    SDECL(0)  SDECL(1)  SDECL(2)  SDECL(3)  SDECL(4)  SDECL(5)  SDECL(6)  SDECL(7)
    SDECL(8)  SDECL(9)  SDECL(10) SDECL(11) SDECL(12) SDECL(13) SDECL(14) SDECL(15)
#pragma unroll 1
    for (int kc = 0; kc < DD; kc += 8) {
        float4 mA0 = *(const float4*)(mA + kc), mA1 = *(const float4*)(mA + kc + 4);
        float4 xA0 = *(const float4*)(xA + kc), xA1 = *(const float4*)(xA + kc + 4);
        float4 mB0 = *(const float4*)(mB + kc), mB1 = *(const float4*)(mB + kc + 4);
        float4 xB0 = *(const float4*)(xB + kc), xB1 = *(const float4*)(xB + kc + 4);
        float4 mC0 = *(const float4*)(mC + kc), mC1 = *(const float4*)(mC + kc + 4);
        float4 xC0 = *(const float4*)(xC + kc), xC1 = *(const float4*)(xC + kc + 4);
        float4 mD0 = *(const float4*)(mD + kc), mD1 = *(const float4*)(mD + kc + 4);
        float4 xD0 = *(const float4*)(xD + kc), xD1 = *(const float4*)(xD + kc + 4);
        SCOL(0)  SCOL(1)  SCOL(2)  SCOL(3)  SCOL(4)  SCOL(5)  SCOL(6)  SCOL(7)
        SCOL(8)  SCOL(9)  SCOL(10) SCOL(11) SCOL(12) SCOL(13) SCOL(14) SCOL(15)
    }
    if (do_relu) {
        SRELU(0)  SRELU(1)  SRELU(2)  SRELU(3)  SRELU(4)  SRELU(5)  SRELU(6)  SRELU(7)
        SRELU(8)  SRELU(9)  SRELU(10) SRELU(11) SRELU(12) SRELU(13) SRELU(14) SRELU(15)
    }
    STORE_ROW(sA, r0)
    STORE_ROW(sB, r0 + 64)
    STORE_ROW(sC, r0 + 128)
    STORE_ROW(sD, r0 + 192)
}

// -------------------- fused SAGE linear (both sides, one launch) -----------
__global__ __launch_bounds__(256, 2)
void sage_fused_kernel(const float* __restrict__ mean_r, const float* __restrict__ hr,
                       const float* __restrict__ mean_u, const float* __restrict__ hu,
                       const float* __restrict__ Wl2, const float* __restrict__ Wr2,
                       const float* __restrict__ bl2,
                       float* __restrict__ out_r, float* __restrict__ out_u, int do_relu) {
    __shared__ float Wls[DD * DD];
    __shared__ float Wrs[DD * DD];
    __shared__ float bsh[DD];
    int side = (blockIdx.x < NBR) ? 0 : 1;
    const float* Wl = Wl2 + side * DD * DD;
    const float* Wr = Wr2 + side * DD * DD;
    const float* bl = bl2 + side * DD;
    for (int i = threadIdx.x; i < DD * DD; i += 256) {
        Wls[i] = Wl[i];
        Wrs[i] = Wr[i];
    }
    if (threadIdx.x < DD) bsh[threadIdx.x] = bl[threadIdx.x];
    __syncthreads();
    int lane = threadIdx.x & 63;
    int cb = (threadIdx.x >> 6) * 16;
    if (side == 0) {
        int r0 = blockIdx.x * 256 + lane;
        sage_tile(mean_r, hr, Wls, Wrs, bsh, out_r, NR, do_relu, r0, cb);
    } else {
        int r0 = (blockIdx.x - NBR) * 256 + lane;
        sage_tile(mean_u, hu, Wls, Wrs, bsh, out_u, NU, do_relu, r0, cb);
    }
}

// -------------------- fused decoder layer-1 precompute ---------------------
#define PCOL(j) { \
    const float4* wp_ = (const float4*)(Ws + ((cb + (j)) << 6) + kc); \
    float4 w0_ = wp_[0], w1_ = wp_[1]; \
    sA##j += DOT4(xA0,w0_)+DOT4(xA1,w1_); \
    sB##j += DOT4(xB0,w0_)+DOT4(xB1,w1_); \
    sC##j += DOT4(xC0,w0_)+DOT4(xC1,w1_); \
    sD##j += DOT4(xD0,w0_)+DOT4(xD1,w1_); }

__device__ __forceinline__
void pre_tile(const float* __restrict__ h, const float* Ws, const float* bsh,
              float* __restrict__ out, int n, int r0, int cb) {
    int rA = min(r0, n - 1), rB = min(r0 + 64, n - 1);
    int rC = min(r0 + 128, n - 1), rD = min(r0 + 192, n - 1);
    const float *xA = h + (size_t)rA * DD, *xB = h + (size_t)rB * DD;
    const float *xC = h + (size_t)rC * DD, *xD = h + (size_t)rD * DD;
    SDECL(0)  SDECL(1)  SDECL(2)  SDECL(3)  SDECL(4)  SDECL(5)  SDECL(6)  SDECL(7)
    SDECL(8)  SDECL(9)  SDECL(10) SDECL(11) SDECL(12) SDECL(13) SDECL(14) SDECL(15)
#pragma unroll 1
    for (int kc = 0; kc < DD; kc += 8) {
        float4 xA0 = *(const float4*)(xA + kc), xA1 = *(const float4*)(xA + kc + 4);
        float4 xB0 = *(const float4*)(xB + kc), xB1 = *(const float4*)(xB + kc + 4);
        float4 xC0 = *(const float4*)(xC + kc), xC1 = *(const float4*)(xC + kc + 4);
        float4 xD0 = *(const float4*)(xD + kc), xD1 = *(const float4*)(xD + kc + 4);
        PCOL(0)  PCOL(1)  PCOL(2)  PCOL(3)  PCOL(4)  PCOL(5)  PCOL(6)  PCOL(7)
        PCOL(8)  PCOL(9)  PCOL(10) PCOL(11) PCOL(12) PCOL(13) PCOL(14) PCOL(15)
    }
    STORE_ROW(sA, r0)
    STORE_ROW(sB, r0 + 64)
    STORE_ROW(sC, r0 + 128)
    STORE_ROW(sD, r0 + 192)
}

__global__ __launch_bounds__(256, 2)
void pre_fused_kernel(const float* __restrict__ hu, const float* __restrict__ hr,
                      const float* __restrict__ dW1, const float* __restrict__ db1,
                      float* __restrict__ P_u, float* __restrict__ P_r) {
    __shared__ float Ws[DD * DD];
    __shared__ float bsh[DD];
    int side = (blockIdx.x < NBU) ? 0 : 1;   // 0 = user (koff 0, bias), 1 = rest
    int koff = side ? DD : 0;
    for (int i = threadIdx.x; i < DD * DD; i += 256) {
        int c = i >> 6, k = i & 63;
        Ws[c * DD + k] = dW1[c * 2 * DD + koff + k];
    }
    if (threadIdx.x < DD) bsh[threadIdx.x] = side ? 0.f : db1[threadIdx.x];
    __syncthreads();
    int lane = threadIdx.x & 63;
    int cb = (threadIdx.x >> 6) * 16;
    if (side == 0) {
        int r0 = blockIdx.x * 256 + lane;
        pre_tile(hu, Ws, bsh, P_u, NU, r0, cb);
    } else {
        int r0 = (blockIdx.x - NBU) * 256 + lane;
        pre_tile(hr, Ws, bsh, P_r, NR, r0, cb);
    }
}

// -------------------- fused decoder: thread per query (R8 form) ------------
#define ZCOMB(Zi, i) float4 Zi; { float4 u_ = pu[i]; float4 v_ = pr[i]; \
    Zi.x = fmaxf(u_.x + v_.x, 0.f); Zi.y = fmaxf(u_.y + v_.y, 0.f); \
    Zi.z = fmaxf(u_.z + v_.z, 0.f); Zi.w = fmaxf(u_.w + v_.w, 0.f); }

__global__ __launch_bounds__(256, 2)
void decoder_kernel(const float* __restrict__ Pu, const float* __restrict__ Pr,
                    const int* __restrict__ el_row, const int* __restrict__ el_col,
                    const float* __restrict__ dW2, const float* __restrict__ db2,
                    const float* __restrict__ dW3, const float* __restrict__ db3,
                    float* __restrict__ out) {
    __shared__ float W2s[DD * DD];
    __shared__ float b2s[DD], w3s[DD];
    for (int i = threadIdx.x; i < DD * DD; i += 256) W2s[i] = dW2[i];
    if (threadIdx.x < DD) {
        b2s[threadIdx.x] = db2[threadIdx.x];
        w3s[threadIdx.x] = dW3[threadIdx.x];
    }
    __syncthreads();
    int q = blockIdx.x * 256 + threadIdx.x;
    if (q >= NQ) return;
    int row = el_row[q], col = el_col[q];
    const float4* pu = (const float4*)(Pu + (size_t)row * DD);
    const float4* pr = (const float4*)(Pr + (size_t)col * DD);
    ZCOMB(z0, 0)  ZCOMB(z1, 1)  ZCOMB(z2, 2)  ZCOMB(z3, 3)
    ZCOMB(z4, 4)  ZCOMB(z5, 5)  ZCOMB(z6, 6)  ZCOMB(z7, 7)
    ZCOMB(z8, 8)  ZCOMB(z9, 9)  ZCOMB(z10, 10) ZCOMB(z11, 11)
    ZCOMB(z12, 12) ZCOMB(z13, 13) ZCOMB(z14, 14) ZCOMB(z15, 15)
    float o = db3[0];
#pragma unroll 2
    for (int c = 0; c < DD; c++) {
        const float4* wp = (const float4*)(W2s + c * DD);  // broadcast, conflict-free
        float s = b2s[c]
            + DOT4(z0, wp[0])  + DOT4(z1, wp[1])  + DOT4(z2, wp[2])  + DOT4(z3, wp[3])
            + DOT4(z4, wp[4])  + DOT4(z5, wp[5])  + DOT4(z6, wp[6])  + DOT4(z7, wp[7])
            + DOT4(z8, wp[8])  + DOT4(z9, wp[9])  + DOT4(z10, wp[10]) + DOT4(z11, wp[11])
            + DOT4(z12, wp[12]) + DOT4(z13, wp[13]) + DOT4(z14, wp[14]) + DOT4(z15, wp[15]);
        o += fmaxf(s, 0.f) * w3s[c];
    }
    out[q] = o;
}

extern "C" void kernel_launch(void* const* d_in, const int* in_sizes, int n_in,
                              void* d_out, int out_size, void* d_ws, size_t ws_size,
                              hipStream_t stream) {
    const float* x_user = (const float*)d_in[0];
    const float* x_rest = (const float*)d_in[1];
    const float* Wl     = (const float*)d_in[2];
    const float* Wr     = (const float*)d_in[3];
    const float* bl     = (const float*)d_in[4];
    const float* dW1    = (const float*)d_in[5];
    const float* db1    = (const float*)d_in[6];
    const float* dW2    = (const float*)d_in[7];
    const float* db2    = (const float*)d_in[8];
    const float* dW3    = (const float*)d_in[9];
    const float* db3    = (const float*)d_in[10];
    const int* ur_src   = (const int*)d_in[11];
    const int* ur_dst   = (const int*)d_in[12];
    const int* ru_src   = (const int*)d_in[13];
    const int* ru_dst   = (const int*)d_in[14];
    const int* el_row   = (const int*)d_in[15];
    const int* el_col   = (const int*)d_in[16];
    float* out = (float*)d_out;

    char* w = (char*)d_ws;
    size_t off = 0;
    auto alloc = [&](size_t bytes) -> void* {
        void* p = (void*)(w + off);
        off += (bytes + 255) & ~(size_t)255;
        return p;
    };
    float* hu0    = (float*)alloc((size_t)NU * DD * 4);
    float* hu1    = (float*)alloc((size_t)NU * DD * 4);
    float* hr0    = (float*)alloc((size_t)NR * DD * 4);
    float* hr1    = (float*)alloc((size_t)NR * DD * 4);
    float* mean_u = (float*)alloc((size_t)NU * DD * 4);
    float* mean_r = (float*)alloc((size_t)NR * DD * 4);
    int* csr_u  = (int*)alloc((size_t)NE * 4);
    int* rs_u   = (int*)alloc((size_t)(NU + 1) * 4);
    int* cnt_r  = (int*)alloc((size_t)NR * 4);
    int* pairs2 = (int*)alloc((size_t)NBS_R * CAP_R * 4);   // 9.6 MB, persistent
    int* bcur   = (int*)alloc((size_t)(NBS_U + NBS_R) * 4);
    int* bbase  = (int*)alloc((size_t)NBS_U * 4);

    // int2 pair buffer carved from mean_u (written only later by gatheru):
    // u-region 98*24576*8 + r-region 196*12288*8 = 38.5MB <= 51.2MB
    int2* pairs = (int2*)mean_u;

    // ---- build: bin by dst window -> u: CSR fill; r: src-sort + degree ----
    hipMemsetAsync(bcur, 0, (size_t)(NBS_U + NBS_R) * 4, stream);
    binpass_kernel<<<2 * NPBB, 256, 0, stream>>>(ru_src, ru_dst, ur_src, ur_dst,
                                                 bcur, pairs);
    ubase_kernel<<<1, 128, 0, stream>>>(bcur, bbase, rs_u);
    fillpassu_kernel<<<NBS_U, 256, 0, stream>>>(pairs, bcur, bbase, rs_u, csr_u);
    srcsort_kernel<<<NBS_R, 256, 0, stream>>>(pairs, bcur, pairs2, cnt_r);

    // ---- 3 SAGE layers ----
    const float* cu = x_user;
    const float* cr = x_rest;
    float* nu_[3] = {hu0, hu1, hu0};
    float* nr_[3] = {hr0, hr1, hr0};
    const int ugrid = (NU + 3) / 4;   // 50000

    for (int l = 0; l < 3; l++) {
        const float* Wl2 = Wl + (size_t)l * 2 * DD * DD;
        const float* Wr2 = Wr + (size_t)l * 2 * DD * DD;
        const float* bl2 = bl + (size_t)l * 2 * DD;
        int relu = (l < 2) ? 1 : 0;
        rscatter_kernel<<<NBS_R, 512, 0, stream>>>(cu, pairs2, bcur, cnt_r, mean_r);
        gatheru_kernel<<<ugrid, 256, 0, stream>>>(cr, csr_u, rs_u, mean_u);
        sage_fused_kernel<<<NBR + NBU, 256, 0, stream>>>(mean_r, cr, mean_u, cu,
                                                         Wl2, Wr2, bl2,
                                                         nr_[l], nu_[l], relu);
        cu = nu_[l];
        cr = nr_[l];
    }
    // ---- decoder ----
    float* P_u = hu1;
    float* P_r = hr1;
    pre_fused_kernel<<<NBU + NBR, 256, 0, stream>>>(cu, cr, dW1, db1, P_u, P_r);
    decoder_kernel<<<(NQ + 255) / 256, 256, 0, stream>>>(P_u, P_r, el_row, el_col,
                                                         dW2, db2, dW3, db3, out);
}

// Round 5
// 1153.247 us; speedup vs baseline: 3.2363x; 3.2363x over previous
//
#include <hip/hip_runtime.h>

#define NU 200000
#define NR 50000
#define DD 64
#define NE 2000000
#define NQ 500000
#define NBR 196   // ceil(NR/256)
#define NBU 782   // ceil(NU/256)

// ---- dst-windowed CSR build parameters ----
#define NBS 98              // dst windows per side
#define BKT_CAP 24576       // pair capacity per window (mean 20480, +28 sigma)
#define LW_U 11             // 2048 users per window
#define LW_R 9              // 512 restaurants per window
#define PB_E 4096           // edges per binpass block
#define NPBB 489            // ceil(NE / PB_E)

// -------------------- binpass: bin (src,dst) pairs by dst window -----------
__global__ __launch_bounds__(256)
void binpass_kernel(const int* __restrict__ ru_src, const int* __restrict__ ru_dst,
                    const int* __restrict__ ur_src, const int* __restrict__ ur_dst,
                    int* __restrict__ bcur, int2* __restrict__ pairs) {
    __shared__ int2 stg[PB_E];
    __shared__ unsigned char gstg[PB_E];
    __shared__ int hist[256];
    __shared__ int sca[256], scb[256];
    __shared__ int gpos[128];
    int side = (blockIdx.x >= NPBB) ? 1 : 0;
    int blk = side ? (blockIdx.x - NPBB) : blockIdx.x;
    const int* src = side ? ur_src : ru_src;
    const int* dst = side ? ur_dst : ru_dst;
    int lw = side ? LW_R : LW_U;
    int* bc = bcur + side * NBS;
    int2* region = pairs + (size_t)side * NBS * BKT_CAP;
    int tid = threadIdx.x;
    hist[tid] = 0;
    __syncthreads();
    int base = blk * PB_E;
    int myg[16]; int myrank[16]; int2 myp[16];
#pragma unroll
    for (int i = 0; i < 16; i++) {
        int e = base + i * 256 + tid;
        if (e < NE) {
            int d = dst[e];
            int g = d >> lw;
            myg[i] = g;
            myp[i] = make_int2(src[e], d);
            myrank[i] = atomicAdd(&hist[g], 1);
        } else myg[i] = -1;
    }
    __syncthreads();
    int h = hist[tid];
    sca[tid] = h;
    __syncthreads();
    int* cur = sca; int* alt = scb;
    for (int off = 1; off < 256; off <<= 1) {
        int x = cur[tid];
        if (tid >= off) x += cur[tid - off];
        alt[tid] = x;
        __syncthreads();
        int* tmp = cur; cur = alt; alt = tmp;
    }
    alt[tid] = cur[tid] - h;          // exclusive base per bucket
    if (tid < NBS && h > 0) gpos[tid] = atomicAdd(&bc[tid], h);
    __syncthreads();
    int* basep = alt;
#pragma unroll
    for (int i = 0; i < 16; i++) {
        if (myg[i] >= 0) {
            int p = basep[myg[i]] + myrank[i];
            stg[p] = myp[i];
            gstg[p] = (unsigned char)myg[i];
        }
    }
    __syncthreads();
    int tot = cur[255];
    for (int i = tid; i < tot; i += 256) {
        int g = gstg[i];
        int o = g * BKT_CAP + gpos[g] + (i - basep[g]);
        region[o] = stg[i];
    }
}

// -------------------- bbase: scan 98 window totals per side ----------------
__global__ void bbase_kernel(const int* __restrict__ bcur, int* __restrict__ bbase,
                             int* __restrict__ rs_u, int* __restrict__ rs_r) {
    __shared__ int a[128], b[128];
    int sidx = blockIdx.x;
    const int* bc = bcur + sidx * NBS;
    int* bb = bbase + sidx * NBS;
    int tid = threadIdx.x;
    a[tid] = (tid < NBS) ? bc[tid] : 0;
    __syncthreads();
    int* cur = a; int* alt = b;
    for (int off = 1; off < 128; off <<= 1) {
        int t = cur[tid];
        if (tid >= off) t += cur[tid - off];
        alt[tid] = t;
        __syncthreads();
        int* tmp = cur; cur = alt; alt = tmp;
    }
    if (tid < NBS) bb[tid] = (tid == 0) ? 0 : cur[tid - 1];
    if (tid == 0) { if (sidx == 0) rs_u[NU] = NE; else rs_r[NR] = NE; }
}

// -------------------- fillpass: per-window count/scan/scatter in LDS -------
__global__ __launch_bounds__(256)
void fillpass_kernel(const int2* __restrict__ pairs, const int* __restrict__ bcur,
                     const int* __restrict__ bbase,
                     int* __restrict__ rs_u, int* __restrict__ rs_r,
                     int* __restrict__ csr_u, int* __restrict__ csr_r) {
    __shared__ int win[BKT_CAP];      // 96 KB CSR window image
    __shared__ int lcnt[2048];        // 8 KB
    __shared__ int lofs[2048];        // 8 KB
    __shared__ int tsc[256], tsc2[256];
    int side = (blockIdx.x >= NBS) ? 1 : 0;
    int bkt = side ? (blockIdx.x - NBS) : blockIdx.x;
    const int2* reg = pairs + ((size_t)side * NBS + bkt) * BKT_CAP;
    int* rs = side ? rs_r : rs_u;
    int* csr = side ? csr_r : csr_u;
    int W = side ? 512 : 2048;
    int lw = side ? LW_R : LW_U;
    int n = side ? NR : NU;
    int d0 = bkt << lw;
    int tot = bcur[side * NBS + bkt];
    int base = bbase[side * NBS + bkt];
    int tid = threadIdx.x;
    for (int i = tid; i < W; i += 256) lcnt[i] = 0;
    __syncthreads();
    // pass 1: local degree count
    for (int i = tid; i < tot; i += 256) {
        int2 p = reg[i];
        atomicAdd(&lcnt[p.y - d0], 1);
    }
    __syncthreads();
    // exclusive scan of W counters (thread-chunked + block scan)
    int per = W >> 8;                 // 8 (user) or 2 (rest)
    int b0 = tid * per;
    int run = 0;
    for (int i = 0; i < per; i++) { int v = lcnt[b0 + i]; lofs[b0 + i] = run; run += v; }
    tsc[tid] = run;
    __syncthreads();
    int* cur = tsc; int* alt = tsc2;
    for (int off = 1; off < 256; off <<= 1) {
        int x = cur[tid];
        if (tid >= off) x += cur[tid - off];
        alt[tid] = x;
        __syncthreads();
        int* tmp = cur; cur = alt; alt = tmp;
    }
    int texcl = cur[tid] - run;
    for (int i = 0; i < per; i++) lofs[b0 + i] += texcl;
    __syncthreads();
    // write rs window (coalesced)
    int wn = min(W, n - d0);
    for (int i = tid; i < wn; i += 256) rs[d0 + i] = base + lofs[i];
    __syncthreads();
    // pass 2: slot assignment via LDS cursor + LDS scatter
    for (int i = tid; i < tot; i += 256) {
        int2 p = reg[i];
        int slot = atomicAdd(&lofs[p.y - d0], 1);
        win[slot] = p.x;
    }
    __syncthreads();
    // stream out (coalesced)
    for (int i = tid; i < tot; i += 256) csr[base + i] = win[i];
}

// -------------------- fused gather mean: wave per dst row, 16x4 groups -----
// 4 groups of 16 lanes; each group loads one neighbor row as float4/lane
// (256B per group-instruction). 2 independent accumulators for MLP.
__global__ __launch_bounds__(256)
void gather2_kernel(const float* __restrict__ hu, const int* __restrict__ csr_r,
                    const int* __restrict__ rs_r, float* __restrict__ mean_r,
                    const float* __restrict__ hr, const int* __restrict__ csr_u,
                    const int* __restrict__ rs_u, float* __restrict__ mean_u) {
    int lane = threadIdx.x & 63;
    int wave = blockIdx.x * 4 + (threadIdx.x >> 6);
    const float* h; const int* csr; const int* rs; float* mean; int r;
    if (wave < NR) { h = hu; csr = csr_r; rs = rs_r; mean = mean_r; r = wave; }
    else if (wave < NR + NU) { h = hr; csr = csr_u; rs = rs_u; mean = mean_u; r = wave - NR; }
    else return;
    int s = rs[r], e = rs[r + 1];
    int g = lane >> 4;            // neighbor subgroup 0..3
    int fo = (lane & 15) << 2;    // feature offset 0,4,...,60
    float4 a0 = {0.f, 0.f, 0.f, 0.f};
    float4 a1 = {0.f, 0.f, 0.f, 0.f};
    for (int j = s; j < e; j += 64) {
        int rem = e - j;
        int nch = rem < 64 ? rem : 64;
        int li = lane < nch ? lane : nch - 1;
        int idx = csr[j + li];
        for (int kk = 0; kk < nch; kk += 8) {
            int j0 = kk + g;          // <= 59
            int j1 = kk + 4 + g;      // <= 63
            int i0 = __shfl(idx, j0);
            int i1 = __shfl(idx, j1);
            float4 x0 = *(const float4*)(h + (size_t)i0 * DD + fo);
            float4 x1 = *(const float4*)(h + (size_t)i1 * DD + fo);
            if (j0 < nch) { a0.x += x0.x; a0.y += x0.y; a0.z += x0.z; a0.w += x0.w; }
            if (j1 < nch) { a1.x += x1.x; a1.y += x1.y; a1.z += x1.z; a1.w += x1.w; }
        }
    }
    float4 acc;
    acc.x = a0.x + a1.x; acc.y = a0.y + a1.y;
    acc.z = a0.z + a1.z; acc.w = a0.w + a1.w;
    acc.x += __shfl_xor(acc.x, 16); acc.y += __shfl_xor(acc.y, 16);
    acc.z += __shfl_xor(acc.z, 16); acc.w += __shfl_xor(acc.w, 16);
    acc.x += __shfl_xor(acc.x, 32); acc.y += __shfl_xor(acc.y, 32);
    acc.z += __shfl_xor(acc.z, 32); acc.w += __shfl_xor(acc.w, 32);
    if (g == 0) {
        float inv = 1.0f / fmaxf((float)(e - s), 1.0f);
        acc.x *= inv; acc.y *= inv; acc.z *= inv; acc.w *= inv;
        *(float4*)(mean + (size_t)r * DD + fo) = acc;
    }
}

// ==== macro toolkit (sage/precompute: 4 rows/thread x 16 cols/wave) ====
#define DOT4(A, B) ((A).x*(B).x + (A).y*(B).y + (A).z*(B).z + (A).w*(B).w)

#define SDECL(j) float sA##j = bsh[cb + (j)], sB##j = sA##j, sC##j = sA##j, sD##j = sA##j;

#define SCOL(j) { \
    const float4* wlp_ = (const float4*)(Wls + ((cb + (j)) << 6) + kc); \
    const float4* wrp_ = (const float4*)(Wrs + ((cb + (j)) << 6) + kc); \
    float4 l0_ = wlp_[0], l1_ = wlp_[1], q0_ = wrp_[0], q1_ = wrp_[1]; \
    sA##j += DOT4(mA0,l0_)+DOT4(mA1,l1_)+DOT4(xA0,q0_)+DOT4(xA1,q1_); \
    sB##j += DOT4(mB0,l0_)+DOT4(mB1,l1_)+DOT4(xB0,q0_)+DOT4(xB1,q1_); \
    sC##j += DOT4(mC0,l0_)+DOT4(mC1,l1_)+DOT4(xC0,q0_)+DOT4(xC1,q1_); \
    sD##j += DOT4(mD0,l0_)+DOT4(mD1,l1_)+DOT4(xD0,q0_)+DOT4(xD1,q1_); }

#define SRELU(j) { sA##j = fmaxf(sA##j,0.f); sB##j = fmaxf(sB##j,0.f); \
                   sC##j = fmaxf(sC##j,0.f); sD##j = fmaxf(sD##j,0.f); }

#define STORE_ROW(SR, rr) if ((rr) < n) { \
    float* o_ = out + (size_t)(rr) * DD + cb; \
    *(float4*)(o_)      = {SR##0,  SR##1,  SR##2,  SR##3}; \
    *(float4*)(o_ + 4)  = {SR##4,  SR##5,  SR##6,  SR##7}; \
    *(float4*)(o_ + 8)  = {SR##8,  SR##9,  SR##10, SR##11}; \
    *(float4*)(o_ + 12) = {SR##12, SR##13, SR##14, SR##15}; }

__device__ __forceinline__
void sage_tile(const float* __restrict__ mean, const float* __restrict__ h,
               const float* Wls, const float* Wrs, const float* bsh,
               float* __restrict__ out, int n, int do_relu, int r0, int cb) {
    int rA = min(r0, n - 1), rB = min(r0 + 64, n - 1);
    int rC = min(r0 + 128, n - 1), rD = min(r0 + 192, n - 1);
    const float *mA = mean + (size_t)rA * DD, *xA = h + (size_t)rA * DD;
    const float *mB = mean + (size_t)rB * DD, *xB = h + (size_t)rB * DD;
    const float *mC = mean + (size_t)rC * DD, *xC = h + (size_t)rC * DD;
    const float *mD = mean + (size_t)rD * DD, *xD = h + (size_t)rD * DD;
    SDECL(0)  SDECL(1)  SDECL(2)  SDECL(3)  SDECL(4)  SDECL(5)  SDECL(6)  SDECL(7)
    SDECL(8)  SDECL(9)  SDECL(10) SDECL(11) SDECL(12) SDECL(13) SDECL(14) SDECL(15)
#pragma unroll 1
    for (int kc = 0; kc < DD; kc += 8) {
        float4 mA0 = *(const float4*)(mA + kc), mA1 = *(const float4*)(mA + kc + 4);
        float4 xA0 = *(const float4*)(xA + kc), xA1 = *(const float4*)(xA + kc + 4);
        float4 mB0 = *(const float4*)(mB + kc), mB1 = *(const float4*)(mB + kc + 4);
        float4 xB0 = *(const float4*)(xB + kc), xB1 = *(const float4*)(xB + kc + 4);
        float4 mC0 = *(const float4*)(mC + kc), mC1 = *(const float4*)(mC + kc + 4);
        float4 xC0 = *(const float4*)(xC + kc), xC1 = *(const float4*)(xC + kc + 4);
        float4 mD0 = *(const float4*)(mD + kc), mD1 = *(const float4*)(mD + kc + 4);
        float4 xD0 = *(const float4*)(xD + kc), xD1 = *(const float4*)(xD + kc + 4);
        SCOL(0)  SCOL(1)  SCOL(2)  SCOL(3)  SCOL(4)  SCOL(5)  SCOL(6)  SCOL(7)
        SCOL(8)  SCOL(9)  SCOL(10) SCOL(11) SCOL(12) SCOL(13) SCOL(14) SCOL(15)
    }
    if (do_relu) {
        SRELU(0)  SRELU(1)  SRELU(2)  SRELU(3)  SRELU(4)  SRELU(5)  SRELU(6)  SRELU(7)
        SRELU(8)  SRELU(9)  SRELU(10) SRELU(11) SRELU(12) SRELU(13) SRELU(14) SRELU(15)
    }
    STORE_ROW(sA, r0)
    STORE_ROW(sB, r0 + 64)
    STORE_ROW(sC, r0 + 128)
    STORE_ROW(sD, r0 + 192)
}

// -------------------- fused SAGE linear (both sides, one launch) -----------
__global__ __launch_bounds__(256, 2)
void sage_fused_kernel(const float* __restrict__ mean_r, const float* __restrict__ hr,
                       const float* __restrict__ mean_u, const float* __restrict__ hu,
                       const float* __restrict__ Wl2, const float* __restrict__ Wr2,
                       const float* __restrict__ bl2,
                       float* __restrict__ out_r, float* __restrict__ out_u, int do_relu) {
    __shared__ float Wls[DD * DD];
    __shared__ float Wrs[DD * DD];
    __shared__ float bsh[DD];
    int side = (blockIdx.x < NBR) ? 0 : 1;
    const float* Wl = Wl2 + side * DD * DD;
    const float* Wr = Wr2 + side * DD * DD;
    const float* bl = bl2 + side * DD;
    for (int i = threadIdx.x; i < DD * DD; i += 256) {
        Wls[i] = Wl[i];
        Wrs[i] = Wr[i];
    }
    if (threadIdx.x < DD) bsh[threadIdx.x] = bl[threadIdx.x];
    __syncthreads();
    int lane = threadIdx.x & 63;
    int cb = (threadIdx.x >> 6) * 16;
    if (side == 0) {
        int r0 = blockIdx.x * 256 + lane;
        sage_tile(mean_r, hr, Wls, Wrs, bsh, out_r, NR, do_relu, r0, cb);
    } else {
        int r0 = (blockIdx.x - NBR) * 256 + lane;
        sage_tile(mean_u, hu, Wls, Wrs, bsh, out_u, NU, do_relu, r0, cb);
    }
}

// -------------------- fused decoder layer-1 precompute ---------------------
#define PCOL(j) { \
    const float4* wp_ = (const float4*)(Ws + ((cb + (j)) << 6) + kc); \
    float4 w0_ = wp_[0], w1_ = wp_[1]; \
    sA##j += DOT4(xA0,w0_)+DOT4(xA1,w1_); \
    sB##j += DOT4(xB0,w0_)+DOT4(xB1,w1_); \
    sC##j += DOT4(xC0,w0_)+DOT4(xC1,w1_); \
    sD##j += DOT4(xD0,w0_)+DOT4(xD1,w1_); }

__device__ __forceinline__
void pre_tile(const float* __restrict__ h, const float* Ws, const float* bsh,
              float* __restrict__ out, int n, int r0, int cb) {
    int rA = min(r0, n - 1), rB = min(r0 + 64, n - 1);
    int rC = min(r0 + 128, n - 1), rD = min(r0 + 192, n - 1);
    const float *xA = h + (size_t)rA * DD, *xB = h + (size_t)rB * DD;
    const float *xC = h + (size_t)rC * DD, *xD = h + (size_t)rD * DD;
    SDECL(0)  SDECL(1)  SDECL(2)  SDECL(3)  SDECL(4)  SDECL(5)  SDECL(6)  SDECL(7)
    SDECL(8)  SDECL(9)  SDECL(10) SDECL(11) SDECL(12) SDECL(13) SDECL(14) SDECL(15)
#pragma unroll 1
    for (int kc = 0; kc < DD; kc += 8) {
        float4 xA0 = *(const float4*)(xA + kc), xA1 = *(const float4*)(xA + kc + 4);
        float4 xB0 = *(const float4*)(xB + kc), xB1 = *(const float4*)(xB + kc + 4);
        float4 xC0 = *(const float4*)(xC + kc), xC1 = *(const float4*)(xC + kc + 4);
        float4 xD0 = *(const float4*)(xD + kc), xD1 = *(const float4*)(xD + kc + 4);
        PCOL(0)  PCOL(1)  PCOL(2)  PCOL(3)  PCOL(4)  PCOL(5)  PCOL(6)  PCOL(7)
        PCOL(8)  PCOL(9)  PCOL(10) PCOL(11) PCOL(12) PCOL(13) PCOL(14) PCOL(15)
    }
    STORE_ROW(sA, r0)
    STORE_ROW(sB, r0 + 64)
    STORE_ROW(sC, r0 + 128)
    STORE_ROW(sD, r0 + 192)
}

__global__ __launch_bounds__(256, 2)
void pre_fused_kernel(const float* __restrict__ hu, const float* __restrict__ hr,
                      const float* __restrict__ dW1, const float* __restrict__ db1,
                      float* __restrict__ P_u, float* __restrict__ P_r) {
    __shared__ float Ws[DD * DD];
    __shared__ float bsh[DD];
    int side = (blockIdx.x < NBU) ? 0 : 1;   // 0 = user (koff 0, bias), 1 = rest
    int koff = side ? DD : 0;
    for (int i = threadIdx.x; i < DD * DD; i += 256) {
        int c = i >> 6, k = i & 63;
        Ws[c * DD + k] = dW1[c * 2 * DD + koff + k];
    }
    if (threadIdx.x < DD) bsh[threadIdx.x] = side ? 0.f : db1[threadIdx.x];
    __syncthreads();
    int lane = threadIdx.x & 63;
    int cb = (threadIdx.x >> 6) * 16;
    if (side == 0) {
        int r0 = blockIdx.x * 256 + lane;
        pre_tile(hu, Ws, bsh, P_u, NU, r0, cb);
    } else {
        int r0 = (blockIdx.x - NBU) * 256 + lane;
        pre_tile(hr, Ws, bsh, P_r, NR, r0, cb);
    }
}

// -------------------- fused decoder: thread per query (R8 form) ------------
#define ZCOMB(Zi, i) float4 Zi; { float4 u_ = pu[i]; float4 v_ = pr[i]; \
    Zi.x = fmaxf(u_.x + v_.x, 0.f); Zi.y = fmaxf(u_.y + v_.y, 0.f); \
    Zi.z = fmaxf(u_.z + v_.z, 0.f); Zi.w = fmaxf(u_.w + v_.w, 0.f); }

__global__ __launch_bounds__(256, 2)
void decoder_kernel(const float* __restrict__ Pu, const float* __restrict__ Pr,
                    const int* __restrict__ el_row, const int* __restrict__ el_col,
                    const float* __restrict__ dW2, const float* __restrict__ db2,
                    const float* __restrict__ dW3, const float* __restrict__ db3,
                    float* __restrict__ out) {
    __shared__ float W2s[DD * DD];
    __shared__ float b2s[DD], w3s[DD];
    for (int i = threadIdx.x; i < DD * DD; i += 256) W2s[i] = dW2[i];
    if (threadIdx.x < DD) {
        b2s[threadIdx.x] = db2[threadIdx.x];
        w3s[threadIdx.x] = dW3[threadIdx.x];
    }
    __syncthreads();
    int q = blockIdx.x * 256 + threadIdx.x;
    if (q >= NQ) return;
    int row = el_row[q], col = el_col[q];
    const float4* pu = (const float4*)(Pu + (size_t)row * DD);
    const float4* pr = (const float4*)(Pr + (size_t)col * DD);
    ZCOMB(z0, 0)  ZCOMB(z1, 1)  ZCOMB(z2, 2)  ZCOMB(z3, 3)
    ZCOMB(z4, 4)  ZCOMB(z5, 5)  ZCOMB(z6, 6)  ZCOMB(z7, 7)
    ZCOMB(z8, 8)  ZCOMB(z9, 9)  ZCOMB(z10, 10) ZCOMB(z11, 11)
    ZCOMB(z12, 12) ZCOMB(z13, 13) ZCOMB(z14, 14) ZCOMB(z15, 15)
    float o = db3[0];
#pragma unroll 2
    for (int c = 0; c < DD; c++) {
        const float4* wp = (const float4*)(W2s + c * DD);  // broadcast, conflict-free
        float s = b2s[c]
            + DOT4(z0, wp[0])  + DOT4(z1, wp[1])  + DOT4(z2, wp[2])  + DOT4(z3, wp[3])
            + DOT4(z4, wp[4])  + DOT4(z5, wp[5])  + DOT4(z6, wp[6])  + DOT4(z7, wp[7])
            + DOT4(z8, wp[8])  + DOT4(z9, wp[9])  + DOT4(z10, wp[10]) + DOT4(z11, wp[11])
            + DOT4(z12, wp[12]) + DOT4(z13, wp[13]) + DOT4(z14, wp[14]) + DOT4(z15, wp[15]);
        o += fmaxf(s, 0.f) * w3s[c];
    }
    out[q] = o;
}

extern "C" void kernel_launch(void* const* d_in, const int* in_sizes, int n_in,
                              void* d_out, int out_size, void* d_ws, size_t ws_size,
                              hipStream_t stream) {
    const float* x_user = (const float*)d_in[0];
    const float* x_rest = (const float*)d_in[1];
    const float* Wl     = (const float*)d_in[2];
    const float* Wr     = (const float*)d_in[3];
    const float* bl     = (const float*)d_in[4];
    const float* dW1    = (const float*)d_in[5];
    const float* db1    = (const float*)d_in[6];
    const float* dW2    = (const float*)d_in[7];
    const float* db2    = (const float*)d_in[8];
    const float* dW3    = (const float*)d_in[9];
    const float* db3    = (const float*)d_in[10];
    const int* ur_src   = (const int*)d_in[11];
    const int* ur_dst   = (const int*)d_in[12];
    const int* ru_src   = (const int*)d_in[13];
    const int* ru_dst   = (const int*)d_in[14];
    const int* el_row   = (const int*)d_in[15];
    const int* el_col   = (const int*)d_in[16];
    float* out = (float*)d_out;

    char* w = (char*)d_ws;
    size_t off = 0;
    auto alloc = [&](size_t bytes) -> void* {
        void* p = (void*)(w + off);
        off += (bytes + 255) & ~(size_t)255;
        return p;
    };
    float* hu0    = (float*)alloc((size_t)NU * DD * 4);
    float* hu1    = (float*)alloc((size_t)NU * DD * 4);
    float* hr0    = (float*)alloc((size_t)NR * DD * 4);
    float* hr1    = (float*)alloc((size_t)NR * DD * 4);
    float* mean_u = (float*)alloc((size_t)NU * DD * 4);
    float* mean_r = (float*)alloc((size_t)NR * DD * 4);
    int* csr_u  = (int*)alloc((size_t)NE * 4);
    int* csr_r  = (int*)alloc((size_t)NE * 4);
    int* rs_u   = (int*)alloc((size_t)(NU + 1) * 4);
    int* rs_r   = (int*)alloc((size_t)(NR + 1) * 4);
    int* bcur   = (int*)alloc((size_t)2 * NBS * 4);
    int* bbase  = (int*)alloc((size_t)2 * NBS * 4);

    // pair buffer carved from mean_u (written only later by gather2):
    // 2 * 98 * 24576 * 8B = 38.5MB <= NU*DD*4 = 51.2MB
    int2* pairs = (int2*)mean_u;

    // ---- CSR build: bin by dst window -> window-local count/scan/fill ----
    hipMemsetAsync(bcur, 0, (size_t)2 * NBS * 4, stream);
    binpass_kernel<<<2 * NPBB, 256, 0, stream>>>(ru_src, ru_dst, ur_src, ur_dst,
                                                 bcur, pairs);
    bbase_kernel<<<2, 128, 0, stream>>>(bcur, bbase, rs_u, rs_r);
    fillpass_kernel<<<2 * NBS, 256, 0, stream>>>(pairs, bcur, bbase,
                                                 rs_u, rs_r, csr_u, csr_r);

    // ---- 3 SAGE layers: 2 fused launches per layer ----
    const float* cu = x_user;
    const float* cr = x_rest;
    float* nu_[3] = {hu0, hu1, hu0};
    float* nr_[3] = {hr0, hr1, hr0};
    const int ggrid = (NR + NU + 3) / 4;   // 62500

    for (int l = 0; l < 3; l++) {
        const float* Wl2 = Wl + (size_t)l * 2 * DD * DD;
        const float* Wr2 = Wr + (size_t)l * 2 * DD * DD;
        const float* bl2 = bl + (size_t)l * 2 * DD;
        int relu = (l < 2) ? 1 : 0;
        gather2_kernel<<<ggrid, 256, 0, stream>>>(cu, csr_r, rs_r, mean_r,
                                                  cr, csr_u, rs_u, mean_u);
        sage_fused_kernel<<<NBR + NBU, 256, 0, stream>>>(mean_r, cr, mean_u, cu,
                                                         Wl2, Wr2, bl2,
                                                         nr_[l], nu_[l], relu);
        cu = nu_[l];
        cr = nr_[l];
    }
    // ---- decoder ----
    float* P_u = hu1;
    float* P_r = hr1;
    pre_fused_kernel<<<NBU + NBR, 256, 0, stream>>>(cu, cr, dW1, db1, P_u, P_r);
    decoder_kernel<<<(NQ + 255) / 256, 256, 0, stream>>>(P_u, P_r, el_row, el_col,
                                                         dW2, db2, dW3, db3, out);
}

// Round 6
// 1001.115 us; speedup vs baseline: 3.7280x; 1.1520x over previous
//
#include <hip/hip_runtime.h>

#define NU 200000
#define NR 50000
#define DD 64
#define NE 2000000
#define NQ 500000
#define NBR 196   // ceil(NR/256)
#define NBU 782   // ceil(NU/256)
#define LDW 68    // padded LDS row stride (68*4B=272B: 16B-aligned, bank-shift 4)

// ---- dst-windowed CSR build parameters ----
#define NBS 98              // dst windows per side
#define BKT_CAP 24576       // pair capacity per window (mean 20480, +28 sigma)
#define LW_U 11             // 2048 users per window
#define LW_R 9              // 512 restaurants per window
#define PB_E 4096           // edges per binpass block
#define NPBB 489            // ceil(NE / PB_E)

// -------------------- binpass: bin (src,dst) pairs by dst window -----------
__global__ __launch_bounds__(256)
void binpass_kernel(const int* __restrict__ ru_src, const int* __restrict__ ru_dst,
                    const int* __restrict__ ur_src, const int* __restrict__ ur_dst,
                    int* __restrict__ bcur, int2* __restrict__ pairs) {
    __shared__ int2 stg[PB_E];
    __shared__ unsigned char gstg[PB_E];
    __shared__ int hist[256];
    __shared__ int sca[256], scb[256];
    __shared__ int gpos[128];
    int side = (blockIdx.x >= NPBB) ? 1 : 0;
    int blk = side ? (blockIdx.x - NPBB) : blockIdx.x;
    const int* src = side ? ur_src : ru_src;
    const int* dst = side ? ur_dst : ru_dst;
    int lw = side ? LW_R : LW_U;
    int* bc = bcur + side * NBS;
    int2* region = pairs + (size_t)side * NBS * BKT_CAP;
    int tid = threadIdx.x;
    hist[tid] = 0;
    __syncthreads();
    int base = blk * PB_E;
    int myg[16]; int myrank[16]; int2 myp[16];
#pragma unroll
    for (int i = 0; i < 16; i++) {
        int e = base + i * 256 + tid;
        if (e < NE) {
            int d = dst[e];
            int g = d >> lw;
            myg[i] = g;
            myp[i] = make_int2(src[e], d);
            myrank[i] = atomicAdd(&hist[g], 1);
        } else myg[i] = -1;
    }
    __syncthreads();
    int h = hist[tid];
    sca[tid] = h;
    __syncthreads();
    int* cur = sca; int* alt = scb;
    for (int off = 1; off < 256; off <<= 1) {
        int x = cur[tid];
        if (tid >= off) x += cur[tid - off];
        alt[tid] = x;
        __syncthreads();
        int* tmp = cur; cur = alt; alt = tmp;
    }
    alt[tid] = cur[tid] - h;          // exclusive base per bucket
    if (tid < NBS && h > 0) gpos[tid] = atomicAdd(&bc[tid], h);
    __syncthreads();
    int* basep = alt;
#pragma unroll
    for (int i = 0; i < 16; i++) {
        if (myg[i] >= 0) {
            int p = basep[myg[i]] + myrank[i];
            stg[p] = myp[i];
            gstg[p] = (unsigned char)myg[i];
        }
    }
    __syncthreads();
    int tot = cur[255];
    for (int i = tid; i < tot; i += 256) {
        int g = gstg[i];
        int o = g * BKT_CAP + gpos[g] + (i - basep[g]);
        region[o] = stg[i];
    }
}

// -------------------- bbase: scan 98 window totals per side ----------------
__global__ void bbase_kernel(const int* __restrict__ bcur, int* __restrict__ bbase,
                             int* __restrict__ rs_u, int* __restrict__ rs_r) {
    __shared__ int a[128], b[128];
    int sidx = blockIdx.x;
    const int* bc = bcur + sidx * NBS;
    int* bb = bbase + sidx * NBS;
    int tid = threadIdx.x;
    a[tid] = (tid < NBS) ? bc[tid] : 0;
    __syncthreads();
    int* cur = a; int* alt = b;
    for (int off = 1; off < 128; off <<= 1) {
        int t = cur[tid];
        if (tid >= off) t += cur[tid - off];
        alt[tid] = t;
        __syncthreads();
        int* tmp = cur; cur = alt; alt = tmp;
    }
    if (tid < NBS) bb[tid] = (tid == 0) ? 0 : cur[tid - 1];
    if (tid == 0) { if (sidx == 0) rs_u[NU] = NE; else rs_r[NR] = NE; }
}

// -------------------- fillpass: per-window count/scan/scatter in LDS -------
__global__ __launch_bounds__(256)
void fillpass_kernel(const int2* __restrict__ pairs, const int* __restrict__ bcur,
                     const int* __restrict__ bbase,
                     int* __restrict__ rs_u, int* __restrict__ rs_r,
                     int* __restrict__ csr_u, int* __restrict__ csr_r) {
    __shared__ int win[BKT_CAP];      // 96 KB CSR window image
    __shared__ int lcnt[2048];        // 8 KB
    __shared__ int lofs[2048];        // 8 KB
    __shared__ int tsc[256], tsc2[256];
    int side = (blockIdx.x >= NBS) ? 1 : 0;
    int bkt = side ? (blockIdx.x - NBS) : blockIdx.x;
    const int2* reg = pairs + ((size_t)side * NBS + bkt) * BKT_CAP;
    int* rs = side ? rs_r : rs_u;
    int* csr = side ? csr_r : csr_u;
    int W = side ? 512 : 2048;
    int lw = side ? LW_R : LW_U;
    int n = side ? NR : NU;
    int d0 = bkt << lw;
    int tot = bcur[side * NBS + bkt];
    int base = bbase[side * NBS + bkt];
    int tid = threadIdx.x;
    for (int i = tid; i < W; i += 256) lcnt[i] = 0;
    __syncthreads();
    // pass 1: local degree count
    for (int i = tid; i < tot; i += 256) {
        int2 p = reg[i];
        atomicAdd(&lcnt[p.y - d0], 1);
    }
    __syncthreads();
    // exclusive scan of W counters (thread-chunked + block scan)
    int per = W >> 8;                 // 8 (user) or 2 (rest)
    int b0 = tid * per;
    int run = 0;
    for (int i = 0; i < per; i++) { int v = lcnt[b0 + i]; lofs[b0 + i] = run; run += v; }
    tsc[tid] = run;
    __syncthreads();
    int* cur = tsc; int* alt = tsc2;
    for (int off = 1; off < 256; off <<= 1) {
        int x = cur[tid];
        if (tid >= off) x += cur[tid - off];
        alt[tid] = x;
        __syncthreads();
        int* tmp = cur; cur = alt; alt = tmp;
    }
    int texcl = cur[tid] - run;
    for (int i = 0; i < per; i++) lofs[b0 + i] += texcl;
    __syncthreads();
    // write rs window (coalesced)
    int wn = min(W, n - d0);
    for (int i = tid; i < wn; i += 256) rs[d0 + i] = base + lofs[i];
    __syncthreads();
    // pass 2: slot assignment via LDS cursor + LDS scatter
    for (int i = tid; i < tot; i += 256) {
        int2 p = reg[i];
        int slot = atomicAdd(&lofs[p.y - d0], 1);
        win[slot] = p.x;
    }
    __syncthreads();
    // stream out (coalesced)
    for (int i = tid; i < tot; i += 256) csr[base + i] = win[i];
}

// -------------------- fused gather mean: wave per dst row, 16x4 groups -----
__global__ __launch_bounds__(256)
void gather2_kernel(const float* __restrict__ hu, const int* __restrict__ csr_r,
                    const int* __restrict__ rs_r, float* __restrict__ mean_r,
                    const float* __restrict__ hr, const int* __restrict__ csr_u,
                    const int* __restrict__ rs_u, float* __restrict__ mean_u) {
    int lane = threadIdx.x & 63;
    int wave = blockIdx.x * 4 + (threadIdx.x >> 6);
    const float* h; const int* csr; const int* rs; float* mean; int r;
    if (wave < NR) { h = hu; csr = csr_r; rs = rs_r; mean = mean_r; r = wave; }
    else if (wave < NR + NU) { h = hr; csr = csr_u; rs = rs_u; mean = mean_u; r = wave - NR; }
    else return;
    int s = rs[r], e = rs[r + 1];
    int g = lane >> 4;            // neighbor subgroup 0..3
    int fo = (lane & 15) << 2;    // feature offset 0,4,...,60
    float4 a0 = {0.f, 0.f, 0.f, 0.f};
    float4 a1 = {0.f, 0.f, 0.f, 0.f};
    for (int j = s; j < e; j += 64) {
        int rem = e - j;
        int nch = rem < 64 ? rem : 64;
        int li = lane < nch ? lane : nch - 1;
        int idx = csr[j + li];
        for (int kk = 0; kk < nch; kk += 8) {
            int j0 = kk + g;          // <= 59
            int j1 = kk + 4 + g;      // <= 63
            int i0 = __shfl(idx, j0);
            int i1 = __shfl(idx, j1);
            float4 x0 = *(const float4*)(h + (size_t)i0 * DD + fo);
            float4 x1 = *(const float4*)(h + (size_t)i1 * DD + fo);
            if (j0 < nch) { a0.x += x0.x; a0.y += x0.y; a0.z += x0.z; a0.w += x0.w; }
            if (j1 < nch) { a1.x += x1.x; a1.y += x1.y; a1.z += x1.z; a1.w += x1.w; }
        }
    }
    float4 acc;
    acc.x = a0.x + a1.x; acc.y = a0.y + a1.y;
    acc.z = a0.z + a1.z; acc.w = a0.w + a1.w;
    acc.x += __shfl_xor(acc.x, 16); acc.y += __shfl_xor(acc.y, 16);
    acc.z += __shfl_xor(acc.z, 16); acc.w += __shfl_xor(acc.w, 16);
    acc.x += __shfl_xor(acc.x, 32); acc.y += __shfl_xor(acc.y, 32);
    acc.z += __shfl_xor(acc.z, 32); acc.w += __shfl_xor(acc.w, 32);
    if (g == 0) {
        float inv = 1.0f / fmaxf((float)(e - s), 1.0f);
        acc.x *= inv; acc.y *= inv; acc.z *= inv; acc.w *= inv;
        *(float4*)(mean + (size_t)r * DD + fo) = acc;
    }
}

#define DOT4(A, B) ((A).x*(B).x + (A).y*(B).y + (A).z*(B).z + (A).w*(B).w)

// -------------------- fused SAGE linear: LDS-staged row tiles --------------
// 4 chunks of 64 rows/block. Stage = coalesced float4; compute = 4rowx4col
// per thread from LDS (W reads 16-lane broadcast, row reads 4-lane bcast).
__global__ __launch_bounds__(256, 2)
void sage_fused_kernel(const float* __restrict__ mean_r, const float* __restrict__ hr,
                       const float* __restrict__ mean_u, const float* __restrict__ hu,
                       const float* __restrict__ Wl2, const float* __restrict__ Wr2,
                       const float* __restrict__ bl2,
                       float* __restrict__ out_r, float* __restrict__ out_u, int do_relu) {
    __shared__ __attribute__((aligned(16))) float Wls[DD * LDW];
    __shared__ __attribute__((aligned(16))) float Wrs[DD * LDW];
    __shared__ __attribute__((aligned(16))) float Ms[64 * LDW];
    __shared__ __attribute__((aligned(16))) float Xs[64 * LDW];
    __shared__ float bsh[DD];
    int side = (blockIdx.x < NBR) ? 0 : 1;
    const float* Wl = Wl2 + side * DD * DD;
    const float* Wr = Wr2 + side * DD * DD;
    const float* bl = bl2 + side * DD;
    const float* mean; const float* h; float* out; int n; int blk;
    if (side == 0) { mean = mean_r; h = hr; out = out_r; n = NR; blk = blockIdx.x; }
    else { mean = mean_u; h = hu; out = out_u; n = NU; blk = blockIdx.x - NBR; }
    int tid = threadIdx.x;
    for (int i = tid; i < DD * DD; i += 256) {
        int c = i >> 6, k = i & 63;
        Wls[c * LDW + k] = Wl[i];
        Wrs[c * LDW + k] = Wr[i];
    }
    if (tid < DD) bsh[tid] = bl[tid];
    int rgrp = tid & 15;
    int cgrp = tid >> 4;
    int cb = cgrp * 4;
    int r00 = blk * 256;
    for (int ch = 0; ch < 4; ch++) {
        int rc0 = r00 + ch * 64;
        __syncthreads();   // LDS reuse guard (also covers W load on ch=0)
        for (int i = tid; i < 1024; i += 256) {
            int row = i >> 4;
            int c4 = (i & 15) << 2;
            int gr = min(rc0 + row, n - 1);
            *(float4*)&Ms[row * LDW + c4] = *(const float4*)(mean + (size_t)gr * DD + c4);
            *(float4*)&Xs[row * LDW + c4] = *(const float4*)(h + (size_t)gr * DD + c4);
        }
        __syncthreads();
        float4 bias = {bsh[cb], bsh[cb + 1], bsh[cb + 2], bsh[cb + 3]};
        float4 acc0 = bias, acc1 = bias, acc2 = bias, acc3 = bias;
#pragma unroll 1
        for (int kc = 0; kc < DD; kc += 8) {
            float4 wl[4][2], wr[4][2];
#pragma unroll
            for (int c = 0; c < 4; c++) {
                wl[c][0] = *(const float4*)&Wls[(cb + c) * LDW + kc];
                wl[c][1] = *(const float4*)&Wls[(cb + c) * LDW + kc + 4];
                wr[c][0] = *(const float4*)&Wrs[(cb + c) * LDW + kc];
                wr[c][1] = *(const float4*)&Wrs[(cb + c) * LDW + kc + 4];
            }
#define SROW(J, ACC) { \
            int row_ = rgrp + 16 * (J); \
            float4 ma_ = *(const float4*)&Ms[row_ * LDW + kc]; \
            float4 mb_ = *(const float4*)&Ms[row_ * LDW + kc + 4]; \
            float4 xa_ = *(const float4*)&Xs[row_ * LDW + kc]; \
            float4 xb_ = *(const float4*)&Xs[row_ * LDW + kc + 4]; \
            ACC.x += DOT4(ma_,wl[0][0])+DOT4(mb_,wl[0][1])+DOT4(xa_,wr[0][0])+DOT4(xb_,wr[0][1]); \
            ACC.y += DOT4(ma_,wl[1][0])+DOT4(mb_,wl[1][1])+DOT4(xa_,wr[1][0])+DOT4(xb_,wr[1][1]); \
            ACC.z += DOT4(ma_,wl[2][0])+DOT4(mb_,wl[2][1])+DOT4(xa_,wr[2][0])+DOT4(xb_,wr[2][1]); \
            ACC.w += DOT4(ma_,wl[3][0])+DOT4(mb_,wl[3][1])+DOT4(xa_,wr[3][0])+DOT4(xb_,wr[3][1]); }
            SROW(0, acc0) SROW(1, acc1) SROW(2, acc2) SROW(3, acc3)
#undef SROW
        }
        if (do_relu) {
            acc0.x = fmaxf(acc0.x, 0.f); acc0.y = fmaxf(acc0.y, 0.f); acc0.z = fmaxf(acc0.z, 0.f); acc0.w = fmaxf(acc0.w, 0.f);
            acc1.x = fmaxf(acc1.x, 0.f); acc1.y = fmaxf(acc1.y, 0.f); acc1.z = fmaxf(acc1.z, 0.f); acc1.w = fmaxf(acc1.w, 0.f);
            acc2.x = fmaxf(acc2.x, 0.f); acc2.y = fmaxf(acc2.y, 0.f); acc2.z = fmaxf(acc2.z, 0.f); acc2.w = fmaxf(acc2.w, 0.f);
            acc3.x = fmaxf(acc3.x, 0.f); acc3.y = fmaxf(acc3.y, 0.f); acc3.z = fmaxf(acc3.z, 0.f); acc3.w = fmaxf(acc3.w, 0.f);
        }
        {
            int r0_ = rc0 + rgrp;
            if (r0_ < n)      *(float4*)(out + (size_t)r0_ * DD + cb) = acc0;
            if (r0_ + 16 < n) *(float4*)(out + (size_t)(r0_ + 16) * DD + cb) = acc1;
            if (r0_ + 32 < n) *(float4*)(out + (size_t)(r0_ + 32) * DD + cb) = acc2;
            if (r0_ + 48 < n) *(float4*)(out + (size_t)(r0_ + 48) * DD + cb) = acc3;
        }
    }
}

// -------------------- fused decoder layer-1 precompute (LDS-staged) --------
__global__ __launch_bounds__(256, 2)
void pre_fused_kernel(const float* __restrict__ hu, const float* __restrict__ hr,
                      const float* __restrict__ dW1, const float* __restrict__ db1,
                      float* __restrict__ P_u, float* __restrict__ P_r) {
    __shared__ __attribute__((aligned(16))) float Ws[DD * LDW];
    __shared__ __attribute__((aligned(16))) float Xs[64 * LDW];
    __shared__ float bsh[DD];
    int side = (blockIdx.x < NBU) ? 0 : 1;   // 0 = user (koff 0, bias), 1 = rest
    int koff = side ? DD : 0;
    const float* h; float* out; int n; int blk;
    if (side == 0) { h = hu; out = P_u; n = NU; blk = blockIdx.x; }
    else { h = hr; out = P_r; n = NR; blk = blockIdx.x - NBU; }
    int tid = threadIdx.x;
    for (int i = tid; i < DD * DD; i += 256) {
        int c = i >> 6, k = i & 63;
        Ws[c * LDW + k] = dW1[c * 2 * DD + koff + k];
    }
    if (tid < DD) bsh[tid] = side ? 0.f : db1[tid];
    int rgrp = tid & 15;
    int cgrp = tid >> 4;
    int cb = cgrp * 4;
    int r00 = blk * 256;
    for (int ch = 0; ch < 4; ch++) {
        int rc0 = r00 + ch * 64;
        __syncthreads();
        for (int i = tid; i < 1024; i += 256) {
            int row = i >> 4;
            int c4 = (i & 15) << 2;
            int gr = min(rc0 + row, n - 1);
            *(float4*)&Xs[row * LDW + c4] = *(const float4*)(h + (size_t)gr * DD + c4);
        }
        __syncthreads();
        float4 bias = {bsh[cb], bsh[cb + 1], bsh[cb + 2], bsh[cb + 3]};
        float4 acc0 = bias, acc1 = bias, acc2 = bias, acc3 = bias;
#pragma unroll 1
        for (int kc = 0; kc < DD; kc += 8) {
            float4 wv[4][2];
#pragma unroll
            for (int c = 0; c < 4; c++) {
                wv[c][0] = *(const float4*)&Ws[(cb + c) * LDW + kc];
                wv[c][1] = *(const float4*)&Ws[(cb + c) * LDW + kc + 4];
            }
#define PROW(J, ACC) { \
            int row_ = rgrp + 16 * (J); \
            float4 xa_ = *(const float4*)&Xs[row_ * LDW + kc]; \
            float4 xb_ = *(const float4*)&Xs[row_ * LDW + kc + 4]; \
            ACC.x += DOT4(xa_,wv[0][0])+DOT4(xb_,wv[0][1]); \
            ACC.y += DOT4(xa_,wv[1][0])+DOT4(xb_,wv[1][1]); \
            ACC.z += DOT4(xa_,wv[2][0])+DOT4(xb_,wv[2][1]); \
            ACC.w += DOT4(xa_,wv[3][0])+DOT4(xb_,wv[3][1]); }
            PROW(0, acc0) PROW(1, acc1) PROW(2, acc2) PROW(3, acc3)
#undef PROW
        }
        {
            int r0_ = rc0 + rgrp;
            if (r0_ < n)      *(float4*)(out + (size_t)r0_ * DD + cb) = acc0;
            if (r0_ + 16 < n) *(float4*)(out + (size_t)(r0_ + 16) * DD + cb) = acc1;
            if (r0_ + 32 < n) *(float4*)(out + (size_t)(r0_ + 32) * DD + cb) = acc2;
            if (r0_ + 48 < n) *(float4*)(out + (size_t)(r0_ + 48) * DD + cb) = acc3;
        }
    }
}

// -------------------- fused decoder: thread per query (R8 form) ------------
#define ZCOMB(Zi, i) float4 Zi; { float4 u_ = pu[i]; float4 v_ = pr[i]; \
    Zi.x = fmaxf(u_.x + v_.x, 0.f); Zi.y = fmaxf(u_.y + v_.y, 0.f); \
    Zi.z = fmaxf(u_.z + v_.z, 0.f); Zi.w = fmaxf(u_.w + v_.w, 0.f); }

__global__ __launch_bounds__(256, 2)
void decoder_kernel(const float* __restrict__ Pu, const float* __restrict__ Pr,
                    const int* __restrict__ el_row, const int* __restrict__ el_col,
                    const float* __restrict__ dW2, const float* __restrict__ db2,
                    const float* __restrict__ dW3, const float* __restrict__ db3,
                    float* __restrict__ out) {
    __shared__ float W2s[DD * DD];
    __shared__ float b2s[DD], w3s[DD];
    for (int i = threadIdx.x; i < DD * DD; i += 256) W2s[i] = dW2[i];
    if (threadIdx.x < DD) {
        b2s[threadIdx.x] = db2[threadIdx.x];
        w3s[threadIdx.x] = dW3[threadIdx.x];
    }
    __syncthreads();
    int q = blockIdx.x * 256 + threadIdx.x;
    if (q >= NQ) return;
    int row = el_row[q], col = el_col[q];
    const float4* pu = (const float4*)(Pu + (size_t)row * DD);
    const float4* pr = (const float4*)(Pr + (size_t)col * DD);
    ZCOMB(z0, 0)  ZCOMB(z1, 1)  ZCOMB(z2, 2)  ZCOMB(z3, 3)
    ZCOMB(z4, 4)  ZCOMB(z5, 5)  ZCOMB(z6, 6)  ZCOMB(z7, 7)
    ZCOMB(z8, 8)  ZCOMB(z9, 9)  ZCOMB(z10, 10) ZCOMB(z11, 11)
    ZCOMB(z12, 12) ZCOMB(z13, 13) ZCOMB(z14, 14) ZCOMB(z15, 15)
    float o = db3[0];
#pragma unroll 2
    for (int c = 0; c < DD; c++) {
        const float4* wp = (const float4*)(W2s + c * DD);  // broadcast, conflict-free
        float s = b2s[c]
            + DOT4(z0, wp[0])  + DOT4(z1, wp[1])  + DOT4(z2, wp[2])  + DOT4(z3, wp[3])
            + DOT4(z4, wp[4])  + DOT4(z5, wp[5])  + DOT4(z6, wp[6])  + DOT4(z7, wp[7])
            + DOT4(z8, wp[8])  + DOT4(z9, wp[9])  + DOT4(z10, wp[10]) + DOT4(z11, wp[11])
            + DOT4(z12, wp[12]) + DOT4(z13, wp[13]) + DOT4(z14, wp[14]) + DOT4(z15, wp[15]);
        o += fmaxf(s, 0.f) * w3s[c];
    }
    out[q] = o;
}

extern "C" void kernel_launch(void* const* d_in, const int* in_sizes, int n_in,
                              void* d_out, int out_size, void* d_ws, size_t ws_size,
                              hipStream_t stream) {
    const float* x_user = (const float*)d_in[0];
    const float* x_rest = (const float*)d_in[1];
    const float* Wl     = (const float*)d_in[2];
    const float* Wr     = (const float*)d_in[3];
    const float* bl     = (const float*)d_in[4];
    const float* dW1    = (const float*)d_in[5];
    const float* db1    = (const float*)d_in[6];
    const float* dW2    = (const float*)d_in[7];
    const float* db2    = (const float*)d_in[8];
    const float* dW3    = (const float*)d_in[9];
    const float* db3    = (const float*)d_in[10];
    const int* ur_src   = (const int*)d_in[11];
    const int* ur_dst   = (const int*)d_in[12];
    const int* ru_src   = (const int*)d_in[13];
    const int* ru_dst   = (const int*)d_in[14];
    const int* el_row   = (const int*)d_in[15];
    const int* el_col   = (const int*)d_in[16];
    float* out = (float*)d_out;

    char* w = (char*)d_ws;
    size_t off = 0;
    auto alloc = [&](size_t bytes) -> void* {
        void* p = (void*)(w + off);
        off += (bytes + 255) & ~(size_t)255;
        return p;
    };
    float* hu0    = (float*)alloc((size_t)NU * DD * 4);
    float* hu1    = (float*)alloc((size_t)NU * DD * 4);
    float* hr0    = (float*)alloc((size_t)NR * DD * 4);
    float* hr1    = (float*)alloc((size_t)NR * DD * 4);
    float* mean_u = (float*)alloc((size_t)NU * DD * 4);
    float* mean_r = (float*)alloc((size_t)NR * DD * 4);
    int* csr_u  = (int*)alloc((size_t)NE * 4);
    int* csr_r  = (int*)alloc((size_t)NE * 4);
    int* rs_u   = (int*)alloc((size_t)(NU + 1) * 4);
    int* rs_r   = (int*)alloc((size_t)(NR + 1) * 4);
    int* bcur   = (int*)alloc((size_t)2 * NBS * 4);
    int* bbase  = (int*)alloc((size_t)2 * NBS * 4);

    // pair buffer carved from mean_u (written only later by gather2):
    // 2 * 98 * 24576 * 8B = 38.5MB <= NU*DD*4 = 51.2MB
    int2* pairs = (int2*)mean_u;

    // ---- CSR build: bin by dst window -> window-local count/scan/fill ----
    hipMemsetAsync(bcur, 0, (size_t)2 * NBS * 4, stream);
    binpass_kernel<<<2 * NPBB, 256, 0, stream>>>(ru_src, ru_dst, ur_src, ur_dst,
                                                 bcur, pairs);
    bbase_kernel<<<2, 128, 0, stream>>>(bcur, bbase, rs_u, rs_r);
    fillpass_kernel<<<2 * NBS, 256, 0, stream>>>(pairs, bcur, bbase,
                                                 rs_u, rs_r, csr_u, csr_r);

    // ---- 3 SAGE layers: 2 fused launches per layer ----
    const float* cu = x_user;
    const float* cr = x_rest;
    float* nu_[3] = {hu0, hu1, hu0};
    float* nr_[3] = {hr0, hr1, hr0};
    const int ggrid = (NR + NU + 3) / 4;   // 62500

    for (int l = 0; l < 3; l++) {
        const float* Wl2 = Wl + (size_t)l * 2 * DD * DD;
        const float* Wr2 = Wr + (size_t)l * 2 * DD * DD;
        const float* bl2 = bl + (size_t)l * 2 * DD;
        int relu = (l < 2) ? 1 : 0;
        gather2_kernel<<<ggrid, 256, 0, stream>>>(cu, csr_r, rs_r, mean_r,
                                                  cr, csr_u, rs_u, mean_u);
        sage_fused_kernel<<<NBR + NBU, 256, 0, stream>>>(mean_r, cr, mean_u, cu,
                                                         Wl2, Wr2, bl2,
                                                         nr_[l], nu_[l], relu);
        cu = nu_[l];
        cr = nr_[l];
    }
    // ---- decoder ----
    float* P_u = hu1;
    float* P_r = hr1;
    pre_fused_kernel<<<NBU + NBR, 256, 0, stream>>>(cu, cr, dW1, db1, P_u, P_r);
    decoder_kernel<<<(NQ + 255) / 256, 256, 0, stream>>>(P_u, P_r, el_row, el_col,
                                                         dW2, db2, dW3, db3, out);
}